// Round 1
// 759.322 us; speedup vs baseline: 1.1980x; 1.1980x over previous
//
#include <hip/hip_runtime.h>
#include <cstdint>
#include <cstddef>

// Problem constants
#define B_  512
#define T_  256
#define D_  256
#define H_  1024
#define K2  512      // effective K = 2*D (x_tilde | m); xm middle third folded into cvec
#define N2  2048     // interleaved outputs: col 2m = z preact (row m), col 2m+1 = h_til preact
#define TC  32       // timesteps per chunk
#define NCHUNK 8     // TC*NCHUNK == T_

// Workspace layout (bytes). Total ~52 MB.
#define OFF_WB    ((size_t)0)                      // bf16 [2048][512]            2 MB
#define OFF_CVEC  ((size_t)2097152)                // f32  [2048]                 8 KB
#define OFF_H     ((size_t)2105344)                // f32  [B][H]                 2 MB
#define OFF_INP2  ((size_t)4202496)                // bf16 [TC*B][512]           16 MB
#define OFF_PQ    ((size_t)20979712)               // f32x2 [NCHUNK][B][H]       32 MB

typedef short   bf16x8 __attribute__((ext_vector_type(8)));   // 8 bf16 (4 VGPRs)
typedef float   f32x4  __attribute__((ext_vector_type(4)));

__device__ __forceinline__ unsigned short f2bf(float f) {
    unsigned int u = __float_as_uint(f);
    u += 0x7fffu + ((u >> 16) & 1u);   // round-to-nearest-even
    return (unsigned short)(u >> 16);
}
__device__ __forceinline__ float bf2f(unsigned short s) {
    return __uint_as_float(((unsigned int)s) << 16);
}
__device__ __forceinline__ void async16(const void* g, void* l) {
    __builtin_amdgcn_global_load_lds(
        (const __attribute__((address_space(1))) void*)g,
        (__attribute__((address_space(3))) void*)l, 16, 0, 0);
}

// ---- Prep: pack effective weight columns [0:D) and [2D:3D) to bf16 [2048][512].
// Row interleave: Wb[2m] = Wz row m, Wb[2m+1] = Wh row m (z/h pairs adjacent). ----
__global__ void build_wb(const float* __restrict__ Wz, const float* __restrict__ Wh,
                         unsigned short* __restrict__ Wb) {
    int e = blockIdx.x * 256 + threadIdx.x;
    int r = e >> 9;
    int k = e & 511;
    int m = r >> 1;
    int col = (k < D_) ? k : (k + D_);             // skip the xm middle third
    float v = (r & 1) ? Wh[(size_t)m * 768 + col]
                      : Wz[(size_t)m * 768 + col];
    Wb[e] = f2bf(v);
}

// ---- Prep: cvec[r] = bias[r] + W[r, D:2D] . xm  (interleaved row order) ----
__global__ void build_cvec(const float* __restrict__ Wz, const float* __restrict__ bz,
                           const float* __restrict__ Wh, const float* __restrict__ bh,
                           const float* __restrict__ xm, float* __restrict__ cvec) {
    int r = blockIdx.x;           // 0..2047
    int m = r >> 1;
    int d = threadIdx.x;          // 0..255
    const float* W = (r & 1) ? (Wh + (size_t)m * 768) : (Wz + (size_t)m * 768);
    float v = W[D_ + d] * xm[d];
    for (int off = 32; off; off >>= 1) v += __shfl_down(v, off);
    __shared__ float red[4];
    if ((d & 63) == 0) red[d >> 6] = v;
    __syncthreads();
    if (d == 0) {
        float bias = (r & 1) ? bh[m] : bz[m];
        cvec[r] = bias + red[0] + red[1] + red[2] + red[3];
    }
}

// ---- Per-chunk: build bf16 inp2 rows; ROW ORDER r = b*TC + tc (t-major within batch)
// so each 128-row GEMM tile holds all 32 timesteps of 4 batches. ----
__global__ void build_inp2(const float* __restrict__ X, const float* __restrict__ Mm,
                           const float* __restrict__ xm, const float* __restrict__ gx,
                           unsigned short* __restrict__ inp2, int chunk) {
    int g = blockIdx.x * 256 + threadIdx.x;        // vec8 id; total TC*B*64
    int r = g >> 6;
    int k = (g & 63) * 8;
    int b  = r >> 5;               // r = b*32 + tc
    int tc = r & 31;
    int t  = chunk * TC + tc;
    unsigned short o[8];
    if (k < D_) {
        int d = k;
        const float4* xp = (const float4*)(X  + ((size_t)b * T_ + t) * D_ + d);
        const float4* mp = (const float4*)(Mm + ((size_t)b * T_ + t) * D_ + d);
        float xs[8], ms[8];
        float4 v;
        v = xp[0]; xs[0]=v.x; xs[1]=v.y; xs[2]=v.z; xs[3]=v.w;
        v = xp[1]; xs[4]=v.x; xs[5]=v.y; xs[6]=v.z; xs[7]=v.w;
        v = mp[0]; ms[0]=v.x; ms[1]=v.y; ms[2]=v.z; ms[3]=v.w;
        v = mp[1]; ms[4]=v.x; ms[5]=v.y; ms[6]=v.z; ms[7]=v.w;
        #pragma unroll
        for (int j = 0; j < 8; j++) {
            float m = ms[j], x = xs[j], mu = xm[d + j], gg = gx[d + j];
            float xh = m * x + (1.f - m) * mu;
            float gd = __expf(-gg * (1.f - m));
            o[j] = f2bf(gd * xh + (1.f - gd) * mu);
        }
    } else {
        int d = k - D_;
        const float4* mp = (const float4*)(Mm + ((size_t)b * T_ + t) * D_ + d);
        float4 m0 = mp[0], m1 = mp[1];
        o[0]=f2bf(m0.x); o[1]=f2bf(m0.y); o[2]=f2bf(m0.z); o[3]=f2bf(m0.w);
        o[4]=f2bf(m1.x); o[5]=f2bf(m1.y); o[6]=f2bf(m1.z); o[7]=f2bf(m1.w);
    }
    uint4 pk;
    pk.x = (unsigned)o[0] | ((unsigned)o[1] << 16);
    pk.y = (unsigned)o[2] | ((unsigned)o[3] << 16);
    pk.z = (unsigned)o[4] | ((unsigned)o[5] << 16);
    pk.w = (unsigned)o[6] | ((unsigned)o[7] << 16);
    *(uint4*)(inp2 + (size_t)r * K2 + k) = pk;
}

// ---- Fused GEMM + activation + chunk-local scan.
// 128x128 tile, BK=32, double-buffered LDS, 2-phase pipeline (T3 minimum):
// issue next tile's global_load_lds BEFORE computing current tile, single
// vmcnt(0)+barrier per iteration (compiler drains vmcnt at the barrier, AFTER MFMA).
// Epilogue: activation -> bf16 repack into padded LDS tile -> per-(b,npair)
// scan over the 32 timesteps -> store only (P,Q) per (chunk,b,n). No gates in HBM.
#define EPAD 140   // LDS epilogue row stride in ushorts (280 B): b16 writes & b32 reads conflict-free
__global__ __launch_bounds__(256) void gemm_scan(
    const unsigned short* __restrict__ A,      // [TC*B][512] bf16, row = b*32+tc
    const unsigned short* __restrict__ W,      // [2048][512] bf16, z/h interleaved
    const float* __restrict__ cvec,            // [2048]
    float2* __restrict__ PQ,                   // [NCHUNK][B][1024]
    int chunk)
{
    // staging: 4 bufs of 128x32 ushorts at 0 / 4096 / 8192 / 12288 (32 KB);
    // epilogue tile 128 x EPAD ushorts (35840 B) aliases the whole thing.
    __shared__ __align__(16) unsigned short sm[128 * EPAD];
    const int tid  = threadIdx.x;
    const int lane = tid & 63;
    const int w    = tid >> 6;
    const int tm = blockIdx.x, tn = blockIdx.y;
    const int wm = w & 1, wn = w >> 1;

    // staging geometry: 8 segments of 16 rows x 32 cols (1 KB); wave w does segs {2w,2w+1}
    const int seg  = w * 2;
    const int srow = seg * 16 + (lane >> 2);
    const int scol = (lane & 3) * 8;
    const int aoff = seg * 512;                         // ushort offset within a buffer
    const unsigned short* aptr = A + (size_t)(tm * 128 + srow) * K2 + scol;
    const unsigned short* bptr = W + (size_t)(tn * 128 + srow) * K2 + scol;

#define STAGE(nxt, k0)                                              \
    { unsigned short* ad = sm + (nxt) * 4096 + aoff;                \
      unsigned short* bd = sm + 8192 + (nxt) * 4096 + aoff;         \
      async16(aptr + (k0),            ad);                          \
      async16(aptr + 16 * K2 + (k0),  ad + 512);                    \
      async16(bptr + (k0),            bd);                          \
      async16(bptr + 16 * K2 + (k0),  bd + 512); }

    f32x4 acc[4][4] = {};

    STAGE(0, 0);
    __syncthreads();                 // compiler drains vmcnt(0) here -> buf0 ready

    for (int t = 0; t < 16; ++t) {
        const int cur = t & 1;
        if (t < 15) STAGE(cur ^ 1, (t + 1) * 32);    // prefetch next tile (in flight over MFMA)
        const unsigned short* Ab = sm + cur * 4096;
        const unsigned short* Bb = sm + 8192 + cur * 4096;
        bf16x8 af[4], bv[4];
        #pragma unroll
        for (int i = 0; i < 4; i++)
            af[i] = *(const bf16x8*)&Ab[(wm*64 + i*16 + (lane & 15)) * 32 + (lane >> 4) * 8];
        #pragma unroll
        for (int j = 0; j < 4; j++)
            bv[j] = *(const bf16x8*)&Bb[(wn*64 + j*16 + (lane & 15)) * 32 + (lane >> 4) * 8];
        #pragma unroll
        for (int i = 0; i < 4; i++)
            #pragma unroll
            for (int j = 0; j < 4; j++)
                acc[i][j] = __builtin_amdgcn_mfma_f32_16x16x32_bf16(af[i], bv[j], acc[i][j], 0, 0, 0);
        __syncthreads();             // single drain point: waits prefetch, frees read buffer
    }
#undef STAGE

    // ---- epilogue: activation (col parity: even=sigmoid(z), odd=tanh(h_til)) -> LDS ----
    const float p = (float)(lane & 1);     // ncol parity == lane parity (all bases even)
    const float sg = 1.f + p;              // sigmoid: 1/(1+e^-v); tanh: 2/(1+e^-2v)-1
    #pragma unroll
    for (int j = 0; j < 4; j++) {
        const int ncol  = tn*128 + wn*64 + j*16 + (lane & 15);
        const int col_l = wn*64 + j*16 + (lane & 15);
        const float cadd = cvec[ncol];
        #pragma unroll
        for (int i = 0; i < 4; i++) {
            const int rbase = wm*64 + i*16 + (lane >> 4) * 4;
            #pragma unroll
            for (int r = 0; r < 4; r++) {
                float v = acc[i][j][r] + cadd;
                float u = __expf(-sg * v);
                float res = sg / (1.f + u) - p;
                sm[(size_t)(rbase + r) * EPAD + col_l] = f2bf(res);
            }
        }
    }
    __syncthreads();

    // ---- chunk-local scan: thread u owns (b_local = u>>6, npair = u&63).
    // h_after = P*h_before + Q with P = prod(1-z_t), Q folded forward. ----
    const int bl = tid >> 6;
    const int np = tid & 63;
    const unsigned int* lds32 = (const unsigned int*)sm;   // EPAD/2 = 70 words per row
    float Pp = 1.f, Qq = 0.f;
    #pragma unroll
    for (int tc = 0; tc < 32; ++tc) {
        unsigned int zw = lds32[(size_t)(bl * 32 + tc) * (EPAD / 2) + np];
        float z  = bf2f((unsigned short)(zw & 0xffff));
        float ht = bf2f((unsigned short)(zw >> 16));
        float om = 1.f - z;
        Qq = om * Qq + z * ht;
        Pp = om * Pp;
    }
    const int bg  = tm * 4 + bl;          // global batch
    const int npg = tn * 64 + np;         // global hidden index (pair id == original H index)
    PQ[((size_t)chunk * B_ + bg) * H_ + npg] = make_float2(Pp, Qq);
}

// ---- Combine the 8 chunk-affine maps: h = P_c*h + Q_c, c = 0..7 ----
__global__ void combine(const float2* __restrict__ PQ, float* __restrict__ hbuf) {
    int v = blockIdx.x * 256 + threadIdx.x;   // B*H threads
    int b = v >> 10;
    int n = v & 1023;
    float h = 0.f;
    #pragma unroll
    for (int c = 0; c < NCHUNK; c++) {
        float2 pq = PQ[((size_t)c * B_ + b) * H_ + n];
        h = pq.x * h + pq.y;
    }
    hbuf[(size_t)b * H_ + n] = h;
}

// ---- Output head: out[b] = sigmoid(h[b,:] . Wout + bout) ----
__global__ void head(const float* __restrict__ hbuf, const float* __restrict__ Wout,
                     const float* __restrict__ bout, float* __restrict__ out) {
    int b = blockIdx.x;
    float s = 0.f;
    for (int n = threadIdx.x; n < H_; n += 256)
        s += hbuf[(size_t)b * H_ + n] * Wout[n];
    for (int off = 32; off; off >>= 1) s += __shfl_down(s, off);
    __shared__ float red[4];
    if ((threadIdx.x & 63) == 0) red[threadIdx.x >> 6] = s;
    __syncthreads();
    if (threadIdx.x == 0) {
        float t = red[0] + red[1] + red[2] + red[3] + bout[0];
        out[b] = 1.f / (1.f + expf(-t));
    }
}

extern "C" void kernel_launch(void* const* d_in, const int* in_sizes, int n_in,
                              void* d_out, int out_size, void* d_ws, size_t ws_size,
                              hipStream_t stream) {
    const float* X    = (const float*)d_in[0];
    const float* Mm   = (const float*)d_in[1];
    const float* xm   = (const float*)d_in[2];
    const float* gx   = (const float*)d_in[3];
    const float* Wz   = (const float*)d_in[4];
    const float* bz   = (const float*)d_in[5];
    // d_in[6]=Wr, d_in[7]=br: dead code in reference (r_t unused) — skipped
    const float* Wh   = (const float*)d_in[8];
    const float* bh   = (const float*)d_in[9];
    const float* Wout = (const float*)d_in[10];
    const float* bout = (const float*)d_in[11];
    float* out = (float*)d_out;

    char* ws = (char*)d_ws;
    unsigned short* Wb    = (unsigned short*)(ws + OFF_WB);
    float*          cvec  = (float*)(ws + OFF_CVEC);
    float*          hbuf  = (float*)(ws + OFF_H);
    unsigned short* inp2  = (unsigned short*)(ws + OFF_INP2);
    float2*         PQ    = (float2*)(ws + OFF_PQ);

    build_wb  <<<dim3(N2 * K2 / 256), dim3(256), 0, stream>>>(Wz, Wh, Wb);
    build_cvec<<<dim3(N2),            dim3(256), 0, stream>>>(Wz, bz, Wh, bh, xm, cvec);

    for (int c = 0; c < NCHUNK; c++) {
        build_inp2<<<dim3(TC * B_ * 64 / 256), dim3(256), 0, stream>>>(X, Mm, xm, gx, inp2, c);
        gemm_scan <<<dim3(TC * B_ / 128, 16),  dim3(256), 0, stream>>>(inp2, Wb, cvec, PQ, c);
    }

    combine<<<dim3(B_ * H_ / 256), dim3(256), 0, stream>>>(PQ, hbuf);
    head   <<<dim3(B_),            dim3(256), 0, stream>>>(hbuf, Wout, bout, out);
}

// Round 2
// 714.434 us; speedup vs baseline: 1.2733x; 1.0628x over previous
//
#include <hip/hip_runtime.h>
#include <cstdint>
#include <cstddef>

// Problem constants
#define B_  512
#define T_  256
#define D_  256
#define H_  1024
#define K2  512      // effective K = 2*D: [ y = m*x | m ]; mu-path folded into cvec/Wb
#define N2  2048     // interleaved outputs: col 2m = z preact, col 2m+1 = h_til preact
#define TC  32       // timesteps per chunk
#define NCHUNK 8     // TC*NCHUNK == T_

// Workspace layout (bytes).
// big mode (ws >= ~172 MB): inp2 holds ALL T rows (128 MB) -> 1 build + 1 gemm dispatch.
// small mode: inp2 16 MB, per-chunk loop (8x build+gemm).
#define OFF_WB    ((size_t)0)                      // bf16 [2048][512]            2 MB
#define OFF_CVEC  ((size_t)2097152)                // f32  [2048]                 8 KB
#define OFF_H     ((size_t)2105344)                // f32  [B][H]                 2 MB
#define OFF_PQ    ((size_t)4202496)                // f32x2 [NCHUNK][B][H]       32 MB
#define OFF_INP2  ((size_t)37756928)               // bf16 [nrows][512]     16/128 MB
#define WS_BIG    ((size_t)171974656)              // OFF_INP2 + 131072*512*2

typedef short   bf16x8 __attribute__((ext_vector_type(8)));   // 8 bf16 (4 VGPRs)
typedef float   f32x4  __attribute__((ext_vector_type(4)));

__device__ __forceinline__ unsigned short f2bf(float f) {
    unsigned int u = __float_as_uint(f);
    u += 0x7fffu + ((u >> 16) & 1u);   // round-to-nearest-even
    return (unsigned short)(u >> 16);
}
__device__ __forceinline__ float bf2f(unsigned short s) {
    return __uint_as_float(((unsigned int)s) << 16);
}
__device__ __forceinline__ void async16(const void* g, void* l) {
    __builtin_amdgcn_global_load_lds(
        (const __attribute__((address_space(1))) void*)g,
        (__attribute__((address_space(3))) void*)l, 16, 0, 0);
}

// ---- Prep: effective weights, bf16 [2048][512], z/h rows interleaved.
// cols [0:D)  = W1 (x_tilde block); cols [D:2D) = W3 - W1*mu (mask block).
// Identity used (M binary): x_tilde = m*x + (1-m)*mu, so
// preact = W1.(m*x) + (W3 - W1*mu).m + [(W1+W2).mu + bias]  ----
__global__ void build_wb(const float* __restrict__ Wz, const float* __restrict__ Wh,
                         const float* __restrict__ xm, unsigned short* __restrict__ Wb) {
    int e = blockIdx.x * 256 + threadIdx.x;        // 2048*512 elems
    int r = e >> 9;
    int k = e & 511;
    int m = r >> 1;
    const float* W = (r & 1) ? (Wh + (size_t)m * 768) : (Wz + (size_t)m * 768);
    float v = (k < D_) ? W[k]
                       : (W[2 * D_ + (k - D_)] - W[k - D_] * xm[k - D_]);
    Wb[e] = f2bf(v);
}

// ---- Prep: cvec[r] = bias[r] + (W1[r,:] + W2[r,:]) . mu  (interleaved row order) ----
__global__ void build_cvec(const float* __restrict__ Wz, const float* __restrict__ bz,
                           const float* __restrict__ Wh, const float* __restrict__ bh,
                           const float* __restrict__ xm, float* __restrict__ cvec) {
    int r = blockIdx.x;           // 0..2047
    int m = r >> 1;
    int d = threadIdx.x;          // 0..255
    const float* W = (r & 1) ? (Wh + (size_t)m * 768) : (Wz + (size_t)m * 768);
    float v = (W[d] + W[D_ + d]) * xm[d];
    for (int off = 32; off; off >>= 1) v += __shfl_down(v, off);
    __shared__ float red[4];
    if ((d & 63) == 0) red[d >> 6] = v;
    __syncthreads();
    if (d == 0) {
        float bias = (r & 1) ? bh[m] : bz[m];
        cvec[r] = bias + red[0] + red[1] + red[2] + red[3];
    }
}

// ---- Build bf16 A rows: [ m*x (0:256) | m (0:256) ].  Row r (within dispatch):
// c = chunk0 + (r>>14); b = (r&16383)>>5; tc = r&31; t = c*TC+tc  (t-major in batch). ----
__global__ void build_inp2(const float* __restrict__ X, const float* __restrict__ Mm,
                           unsigned short* __restrict__ inp2, int chunk0) {
    int g = blockIdx.x * 256 + threadIdx.x;        // vec8 id
    int r = g >> 6;
    int k = (g & 63) * 8;
    int c  = chunk0 + (r >> 14);
    int rl = r & 16383;
    int b  = rl >> 5;
    int tc = rl & 31;
    int t  = c * TC + tc;
    int d  = (k < D_) ? k : (k - D_);
    const float4* mp = (const float4*)(Mm + ((size_t)b * T_ + t) * D_ + d);
    float4 m0 = mp[0], m1 = mp[1];
    unsigned short o[8];
    if (k < D_) {
        const float4* xp = (const float4*)(X + ((size_t)b * T_ + t) * D_ + d);
        float4 x0 = xp[0], x1 = xp[1];
        o[0]=f2bf(m0.x*x0.x); o[1]=f2bf(m0.y*x0.y); o[2]=f2bf(m0.z*x0.z); o[3]=f2bf(m0.w*x0.w);
        o[4]=f2bf(m1.x*x1.x); o[5]=f2bf(m1.y*x1.y); o[6]=f2bf(m1.z*x1.z); o[7]=f2bf(m1.w*x1.w);
    } else {
        o[0]=f2bf(m0.x); o[1]=f2bf(m0.y); o[2]=f2bf(m0.z); o[3]=f2bf(m0.w);
        o[4]=f2bf(m1.x); o[5]=f2bf(m1.y); o[6]=f2bf(m1.z); o[7]=f2bf(m1.w);
    }
    uint4 pk;
    pk.x = (unsigned)o[0] | ((unsigned)o[1] << 16);
    pk.y = (unsigned)o[2] | ((unsigned)o[3] << 16);
    pk.z = (unsigned)o[4] | ((unsigned)o[5] << 16);
    pk.w = (unsigned)o[6] | ((unsigned)o[7] << 16);
    *(uint4*)(inp2 + (size_t)r * K2 + k) = pk;
}

// ---- Fused GEMM + activation + chunk-local scan.
// grid = (tn=16, tm_tiles): tn FASTEST -> the 16 blocks of one A-panel run
// concurrently (A-tile L2-hit, A streamed ~once from HBM; W 2MB L2-resident).
// 128x128 tile, BK=32, 2-phase double-buffered LDS pipeline, single barrier/iter.
// Epilogue: activation -> padded LDS tile -> per-(b,npair) affine scan over 32
// timesteps -> store (P,Q) per (chunk,b,n). No gates in HBM.
#define EPAD 140   // LDS epilogue row stride in ushorts: b16 writes & b32 reads conflict-free
__global__ __launch_bounds__(256) void gemm_scan(
    const unsigned short* __restrict__ A,      // [rows][512] bf16, row = c*16384 + b*32 + tc
    const unsigned short* __restrict__ W,      // [2048][512] bf16, z/h interleaved
    const float* __restrict__ cvec,            // [2048]
    float2* __restrict__ PQ,                   // [NCHUNK][B][1024]
    int chunk0)
{
    __shared__ __align__(16) unsigned short sm[128 * EPAD];
    const int tid  = threadIdx.x;
    const int lane = tid & 63;
    const int w    = tid >> 6;
    const int tn = blockIdx.x, tmg = blockIdx.y;
    const int wm = w & 1, wn = w >> 1;

    // staging: 8 segments of 16 rows x 32 cols (1 KB); wave w does segs {2w,2w+1}
    const int seg  = w * 2;
    const int srow = seg * 16 + (lane >> 2);
    const int scol = (lane & 3) * 8;
    const int aoff = seg * 512;                         // ushort offset within a buffer
    const unsigned short* aptr = A + (size_t)(tmg * 128 + srow) * K2 + scol;
    const unsigned short* bptr = W + (size_t)(tn * 128 + srow) * K2 + scol;

#define STAGE(nxt, k0)                                              \
    { unsigned short* ad = sm + (nxt) * 4096 + aoff;                \
      unsigned short* bd = sm + 8192 + (nxt) * 4096 + aoff;         \
      async16(aptr + (k0),            ad);                          \
      async16(aptr + 16 * K2 + (k0),  ad + 512);                    \
      async16(bptr + (k0),            bd);                          \
      async16(bptr + 16 * K2 + (k0),  bd + 512); }

    f32x4 acc[4][4] = {};

    STAGE(0, 0);
    __syncthreads();                 // vmcnt(0) drain -> buf0 ready

    for (int t = 0; t < 16; ++t) {
        const int cur = t & 1;
        if (t < 15) STAGE(cur ^ 1, (t + 1) * 32);    // prefetch in flight over MFMA
        const unsigned short* Ab = sm + cur * 4096;
        const unsigned short* Bb = sm + 8192 + cur * 4096;
        bf16x8 af[4], bv[4];
        #pragma unroll
        for (int i = 0; i < 4; i++)
            af[i] = *(const bf16x8*)&Ab[(wm*64 + i*16 + (lane & 15)) * 32 + (lane >> 4) * 8];
        #pragma unroll
        for (int j = 0; j < 4; j++)
            bv[j] = *(const bf16x8*)&Bb[(wn*64 + j*16 + (lane & 15)) * 32 + (lane >> 4) * 8];
        #pragma unroll
        for (int i = 0; i < 4; i++)
            #pragma unroll
            for (int j = 0; j < 4; j++)
                acc[i][j] = __builtin_amdgcn_mfma_f32_16x16x32_bf16(af[i], bv[j], acc[i][j], 0, 0, 0);
        __syncthreads();             // single drain point: waits prefetch, frees read buffer
    }
#undef STAGE

    // ---- epilogue: activation (col parity: even=sigmoid(z), odd=tanh(h_til)) -> LDS ----
    const float p = (float)(lane & 1);     // ncol parity == lane parity (all bases even)
    const float sg = 1.f + p;              // sigmoid: 1/(1+e^-v); tanh: 2/(1+e^-2v)-1
    #pragma unroll
    for (int j = 0; j < 4; j++) {
        const int ncol  = tn*128 + wn*64 + j*16 + (lane & 15);
        const int col_l = wn*64 + j*16 + (lane & 15);
        const float cadd = cvec[ncol];
        #pragma unroll
        for (int i = 0; i < 4; i++) {
            const int rbase = wm*64 + i*16 + (lane >> 4) * 4;
            #pragma unroll
            for (int r = 0; r < 4; r++) {
                float v = acc[i][j][r] + cadd;
                float u = __expf(-sg * v);
                float res = sg / (1.f + u) - p;
                sm[(size_t)(rbase + r) * EPAD + col_l] = f2bf(res);
            }
        }
    }
    __syncthreads();

    // ---- chunk-local scan: thread u owns (b_local = u>>6, npair = u&63).
    // h_after = P*h_before + Q with P = prod(1-z_t), Q folded forward. ----
    const int bl = tid >> 6;
    const int np = tid & 63;
    const unsigned int* lds32 = (const unsigned int*)sm;   // EPAD/2 = 70 words per row
    float Pp = 1.f, Qq = 0.f;
    #pragma unroll
    for (int tc = 0; tc < 32; ++tc) {
        unsigned int zw = lds32[(size_t)(bl * 32 + tc) * (EPAD / 2) + np];
        float z  = bf2f((unsigned short)(zw & 0xffff));
        float ht = bf2f((unsigned short)(zw >> 16));
        float om = 1.f - z;
        Qq = om * Qq + z * ht;
        Pp = om * Pp;
    }
    const int c   = chunk0 + (tmg >> 7);
    const int bg  = (tmg & 127) * 4 + bl;     // global batch
    const int npg = tn * 64 + np;             // global hidden index
    PQ[((size_t)c * B_ + bg) * H_ + npg] = make_float2(Pp, Qq);
}

// ---- Combine the 8 chunk-affine maps: h = P_c*h + Q_c, c = 0..7 ----
__global__ void combine(const float2* __restrict__ PQ, float* __restrict__ hbuf) {
    int v = blockIdx.x * 256 + threadIdx.x;   // B*H threads
    int b = v >> 10;
    int n = v & 1023;
    float h = 0.f;
    #pragma unroll
    for (int c = 0; c < NCHUNK; c++) {
        float2 pq = PQ[((size_t)c * B_ + b) * H_ + n];
        h = pq.x * h + pq.y;
    }
    hbuf[(size_t)b * H_ + n] = h;
}

// ---- Output head: out[b] = sigmoid(h[b,:] . Wout + bout) ----
__global__ void head(const float* __restrict__ hbuf, const float* __restrict__ Wout,
                     const float* __restrict__ bout, float* __restrict__ out) {
    int b = blockIdx.x;
    float s = 0.f;
    for (int n = threadIdx.x; n < H_; n += 256)
        s += hbuf[(size_t)b * H_ + n] * Wout[n];
    for (int off = 32; off; off >>= 1) s += __shfl_down(s, off);
    __shared__ float red[4];
    if ((threadIdx.x & 63) == 0) red[threadIdx.x >> 6] = s;
    __syncthreads();
    if (threadIdx.x == 0) {
        float t = red[0] + red[1] + red[2] + red[3] + bout[0];
        out[b] = 1.f / (1.f + expf(-t));
    }
}

extern "C" void kernel_launch(void* const* d_in, const int* in_sizes, int n_in,
                              void* d_out, int out_size, void* d_ws, size_t ws_size,
                              hipStream_t stream) {
    const float* X    = (const float*)d_in[0];
    const float* Mm   = (const float*)d_in[1];
    const float* xm   = (const float*)d_in[2];
    // d_in[3]=gamma_x: algebraically irrelevant for binary masks (x_tilde == m*x+(1-m)*mu)
    const float* Wz   = (const float*)d_in[4];
    const float* bz   = (const float*)d_in[5];
    // d_in[6]=Wr, d_in[7]=br: dead code in reference (r_t unused) — skipped
    const float* Wh   = (const float*)d_in[8];
    const float* bh   = (const float*)d_in[9];
    const float* Wout = (const float*)d_in[10];
    const float* bout = (const float*)d_in[11];
    float* out = (float*)d_out;

    char* ws = (char*)d_ws;
    unsigned short* Wb    = (unsigned short*)(ws + OFF_WB);
    float*          cvec  = (float*)(ws + OFF_CVEC);
    float*          hbuf  = (float*)(ws + OFF_H);
    float2*         PQ    = (float2*)(ws + OFF_PQ);
    unsigned short* inp2  = (unsigned short*)(ws + OFF_INP2);

    build_wb  <<<dim3(N2 * K2 / 256), dim3(256), 0, stream>>>(Wz, Wh, xm, Wb);
    build_cvec<<<dim3(N2),            dim3(256), 0, stream>>>(Wz, bz, Wh, bh, xm, cvec);

    if (ws_size >= WS_BIG) {
        // one build over all T, one 16384-block GEMM (tn-fastest for A reuse)
        build_inp2<<<dim3(NCHUNK * TC * B_ * 64 / 256), dim3(256), 0, stream>>>(X, Mm, inp2, 0);
        gemm_scan <<<dim3(16, NCHUNK * TC * B_ / 128),  dim3(256), 0, stream>>>(inp2, Wb, cvec, PQ, 0);
    } else {
        for (int c = 0; c < NCHUNK; c++) {
            build_inp2<<<dim3(TC * B_ * 64 / 256), dim3(256), 0, stream>>>(X, Mm, inp2, c);
            gemm_scan <<<dim3(16, TC * B_ / 128),  dim3(256), 0, stream>>>(inp2, Wb, cvec, PQ, c);
        }
    }

    combine<<<dim3(B_ * H_ / 256), dim3(256), 0, stream>>>(PQ, hbuf);
    head   <<<dim3(B_),            dim3(256), 0, stream>>>(hbuf, Wout, bout, out);
}